// Round 1
// baseline (143.192 us; speedup 1.0000x reference)
//
#include <hip/hip_runtime.h>
#include <hip/hip_bf16.h>

typedef short short8 __attribute__((ext_vector_type(8)));
typedef float f32x4 __attribute__((ext_vector_type(4)));
typedef unsigned short u16;

// ---------------- workspace layout (bytes) ----------------
// xTpad bf16 [2][78][78][512]  (x transposed to pos-major, halo 7, zero pad)
#define XT_ELEMS (2*78*78*512)
#define XT_OFF   0
// Wr bf16 [2 conv][9 tap][128 oc][512 c]
#define WR_ELEMS (2*9*128*512)
#define WR_OFF   (XT_OFF + XT_ELEMS*2)            // 12,460,032
// convacc fp32 [4 unit][4096 pos][128 oc]  (unit = conv*2 + b)
#define CA_ELEMS (4*4096*128)
#define CA_OFF   (WR_OFF + WR_ELEMS*2)            // 14,819,328
// gapacc fp32 [4 unit][128]
#define GA_ELEMS (4*128)
#define GA_OFF   (CA_OFF + CA_ELEMS*4)            // 23,207,936
// cvec fp32 [2 b][512]
#define CV_ELEMS (2*512)
#define CV_OFF   (GA_OFF + GA_ELEMS*4)            // 23,209,984
#define WS_TOTAL (CV_OFF + CV_ELEMS*4)            // 23,214,080 B (~22.1 MB) needed

// ---------------- zero fill ----------------
__global__ void zero_u4(uint4* __restrict__ p, int n) {
  int i = blockIdx.x * blockDim.x + threadIdx.x;
  int st = gridDim.x * blockDim.x;
  uint4 z = {0u, 0u, 0u, 0u};
  for (; i < n; i += st) p[i] = z;
}

// ---------------- x -> xTpad (fp32 NCHW -> bf16 [b][h+7][w+7][c]) ----------------
__global__ void prep_x(const float* __restrict__ x, u16* __restrict__ xT) {
  __shared__ float tile[64][65];
  int b = blockIdx.x >> 6, h = blockIdx.x & 63;
  int t = threadIdx.x;
  int w = t & 63, cq = t >> 6;   // load mapping
  int pi = t >> 2, q = t & 3;    // store mapping
  for (int cc = 0; cc < 8; ++cc) {
#pragma unroll
    for (int i = 0; i < 16; ++i) {
      int ci = cq + i * 4;
      tile[ci][w] = x[((b * 512 + cc * 64 + ci) * 4096) + h * 64 + w];
    }
    __syncthreads();
    union { u16 u[16]; uint4 v[2]; } pk;
#pragma unroll
    for (int k = 0; k < 16; ++k) {
      __hip_bfloat16 hb = __float2bfloat16(tile[q * 16 + k][pi]);
      pk.u[k] = *(u16*)&hb;
    }
    u16* dst = xT + ((size_t)(b * 78 + h + 7) * 78 + (pi + 7)) * 512 + cc * 64 + q * 16;
    *(uint4*)dst = pk.v[0];
    *(uint4*)(dst + 8) = pk.v[1];
    __syncthreads();
  }
}

// ---------------- W (OIHW fp32) -> Wr bf16 [conv][tap][oc][c] ----------------
__global__ void prep_w(const float* __restrict__ W2, const float* __restrict__ W4,
                       u16* __restrict__ Wr) {
  __shared__ float sw[4608];
  int conv = blockIdx.x >> 7, o = blockIdx.x & 127;
  const float* W = conv ? W4 : W2;
  int t = threadIdx.x;
#pragma unroll
  for (int k = 0; k < 18; ++k) sw[t * 18 + k] = W[o * 4608 + t * 18 + k];
  __syncthreads();
  for (int tap = 0; tap < 9; ++tap) {
    __hip_bfloat16 h0 = __float2bfloat16(sw[(2 * t) * 9 + tap]);
    __hip_bfloat16 h1 = __float2bfloat16(sw[(2 * t + 1) * 9 + tap]);
    unsigned int u = ((unsigned int)(*(u16*)&h1) << 16) | (unsigned int)(*(u16*)&h0);
    ((unsigned int*)(Wr + ((size_t)(conv * 9 + tap) * 128 + o) * 512))[t] = u;
  }
}

// ---------------- dilated conv partial sums via MFMA ----------------
// grid 384 = 64 groups(b,ptile) x {conv 2}x{kg 3}; WG tile: 128 pos x 128 oc, K = 3 taps x 512
__global__ __launch_bounds__(256) void conv_gap(
    const u16* __restrict__ xT, const u16* __restrict__ Wr,
    float* __restrict__ convacc) {
  __shared__ u16 lds[2][10240];  // per buf: A 128x40u16 (80B pitch) | B 128x40u16
  int bid = blockIdx.x;
  int g = bid / 6, r = bid % 6;
  int conv = r / 3, kg = r % 3;        // kg == kh
  int b = g >> 5, ptile = g & 31;
  int h0 = ptile * 2;
  int d = conv ? 7 : 3;
  int unit = conv * 2 + b;
  const u16* xb = xT + (size_t)b * 78 * 78 * 512;
  const u16* wb = Wr + (size_t)conv * 9 * 128 * 512;
  int t = threadIdx.x, lane = t & 63, wave = t >> 6;
  int wm = wave >> 1, wn = wave & 1;   // wave tile: pos [wm*64,+64), oc [wn*64,+64)
  // staging: thread t owns row t>>1 (both A-pos-row and B-oc-row), 2 of 4 16B slots
  int arow = t >> 1, slot = (t & 1) * 2;
  int hr = h0 + (arow >> 6), wq = arow & 63;
  int arowbase = ((hr + (kg - 1) * d + 7) * 78 + wq + 7) * 512;  // dw added per-step

  f32x4 acc[4][4];
#pragma unroll
  for (int i = 0; i < 4; ++i)
#pragma unroll
    for (int j = 0; j < 4; ++j) acc[i][j] = (f32x4){0.f, 0.f, 0.f, 0.f};

  uint4 ra0, ra1, rb0, rb1;
  auto load_s = [&](int s) {
    int tl = s >> 4, kc = s & 15;      // tap-local, k-chunk
    int c0 = kc * 32;
    int aoff = arowbase + ((tl - 1) * d) * 512 + c0 + slot * 8;
    ra0 = *(const uint4*)(xb + aoff);
    ra1 = *(const uint4*)(xb + aoff + 8);
    int tap = kg * 3 + tl;
    int boff = (tap * 128 + arow) * 512 + c0 + slot * 8;
    rb0 = *(const uint4*)(wb + boff);
    rb1 = *(const uint4*)(wb + boff + 8);
  };
  load_s(0);
  for (int s = 0; s < 48; ++s) {
    u16* L = lds[s & 1];
    *(uint4*)&L[arow * 40 + slot * 8] = ra0;
    *(uint4*)&L[arow * 40 + slot * 8 + 8] = ra1;
    *(uint4*)&L[5120 + arow * 40 + slot * 8] = rb0;
    *(uint4*)&L[5120 + arow * 40 + slot * 8 + 8] = rb1;
    if (s + 1 < 48) load_s(s + 1);
    __syncthreads();
    const u16* A = lds[s & 1];
    const u16* B = lds[s & 1] + 5120;
    short8 af[4], bf[4];
#pragma unroll
    for (int mi = 0; mi < 4; ++mi)
      af[mi] = *(const short8*)&A[(wm * 64 + mi * 16 + (lane & 15)) * 40 + (lane >> 4) * 8];
#pragma unroll
    for (int ni = 0; ni < 4; ++ni)
      bf[ni] = *(const short8*)&B[(wn * 64 + ni * 16 + (lane & 15)) * 40 + (lane >> 4) * 8];
#pragma unroll
    for (int mi = 0; mi < 4; ++mi)
#pragma unroll
      for (int ni = 0; ni < 4; ++ni)
        acc[mi][ni] = __builtin_amdgcn_mfma_f32_16x16x32_bf16(af[mi], bf[ni], acc[mi][ni], 0, 0, 0);
  }
  float* ca = convacc + (size_t)unit * 4096 * 128;
#pragma unroll
  for (int mi = 0; mi < 4; ++mi)
#pragma unroll
    for (int ni = 0; ni < 4; ++ni)
#pragma unroll
      for (int j = 0; j < 4; ++j) {
        int pos = h0 * 64 + wm * 64 + mi * 16 + (lane >> 4) * 4 + j;
        int oc = wn * 64 + ni * 16 + (lane & 15);
        atomicAdd(&ca[pos * 128 + oc], acc[mi][ni][j]);
      }
}

// ---------------- bias + relu + GAP ----------------
__global__ void reduce_gap(const float* __restrict__ convacc,
                           const float* __restrict__ b2, const float* __restrict__ b4,
                           float* __restrict__ gapacc) {
  int unit = blockIdx.x >> 5, chunk = blockIdx.x & 31;
  int conv = unit >> 1;
  const float* bias = conv ? b4 : b2;
  int t = threadIdx.x, oc = t & 127, half = t >> 7;
  const float* ca = convacc + (size_t)unit * 4096 * 128;
  float bi = bias[oc];
  float s = 0.f;
  for (int i = 0; i < 64; ++i) {
    int pos = chunk * 128 + half * 64 + i;
    float v = ca[pos * 128 + oc] + bi;
    s += v > 0.f ? v : 0.f;
  }
  __shared__ float red[2][128];
  red[half][oc] = s;
  __syncthreads();
  if (t < 128) atomicAdd(&gapacc[unit * 128 + t], red[0][t] + red[1][t]);
}

// ---------------- Wd2*(Wcc*(Wd*gap)+bcc), both branches summed ----------------
__global__ void dense_chain(const float* __restrict__ gapacc,
                            const float* __restrict__ Wd, const float* __restrict__ Wcc,
                            const float* __restrict__ bcc, const float* __restrict__ Wd2,
                            float* __restrict__ cvec) {
  int b = blockIdx.x, t = threadIdx.x;  // 512 threads
  __shared__ float gap[2][128], gv[2][512], zv[2][256];
  if (t < 128) gap[0][t] = gapacc[(2 + b) * 128 + t] * (1.f / 4096.f);          // gap4
  else if (t < 256) gap[1][t - 128] = gapacc[b * 128 + (t - 128)] * (1.f / 4096.f);  // gap2
  __syncthreads();
  {
    float s0 = 0.f, s1 = 0.f;
    for (int c = 0; c < 128; ++c) {
      float w = Wd[t * 128 + c];
      s0 += w * gap[0][c];
      s1 += w * gap[1][c];
    }
    gv[0][t] = s0; gv[1][t] = s1;
  }
  __syncthreads();
  {
    int br = t >> 8, o = t & 255;
    float s = bcc[o];
    for (int c = 0; c < 512; ++c) s += Wcc[o * 512 + c] * gv[br][c];
    zv[br][o] = s;
  }
  __syncthreads();
  {
    float s = 0.f;
    for (int c = 0; c < 256; ++c) s += Wd2[t * 256 + c] * (zv[0][c] + zv[1][c]);
    cvec[b * 512 + t] = s;
  }
}

// ---------------- out = x + cvec[b][ch] ----------------
__global__ void final_add(const float* __restrict__ x, const float* __restrict__ cvec,
                          float* __restrict__ out) {
  int i = blockIdx.x * blockDim.x + threadIdx.x;
  int st = gridDim.x * blockDim.x;
  const float4* x4 = (const float4*)x;
  float4* o4 = (float4*)out;
  for (; i < 1048576; i += st) {
    int flat = i << 2;
    int b = flat >> 21;
    int ch = (flat >> 12) & 511;
    float c = cvec[b * 512 + ch];
    float4 v = x4[i];
    v.x += c; v.y += c; v.z += c; v.w += c;
    o4[i] = v;
  }
}

extern "C" void kernel_launch(void* const* d_in, const int* in_sizes, int n_in,
                              void* d_out, int out_size, void* d_ws, size_t ws_size,
                              hipStream_t stream) {
  const float* x   = (const float*)d_in[0];
  const float* W2  = (const float*)d_in[3];
  const float* b2  = (const float*)d_in[4];
  const float* W4  = (const float*)d_in[7];
  const float* b4  = (const float*)d_in[8];
  const float* Wd  = (const float*)d_in[9];
  const float* Wcc = (const float*)d_in[10];
  const float* bcc = (const float*)d_in[11];
  const float* Wd2 = (const float*)d_in[12];
  float* out = (float*)d_out;

  char* ws = (char*)d_ws;
  u16*   xT      = (u16*)(ws + XT_OFF);
  u16*   Wr      = (u16*)(ws + WR_OFF);
  float* convacc = (float*)(ws + CA_OFF);
  float* gapacc  = (float*)(ws + GA_OFF);
  float* cvec    = (float*)(ws + CV_OFF);

  // zero xTpad (halo stays 0) and the accumulators (atomics need clean state every call)
  zero_u4<<<512, 256, 0, stream>>>((uint4*)xT, XT_ELEMS * 2 / 16);
  zero_u4<<<512, 256, 0, stream>>>((uint4*)convacc, (CA_ELEMS + GA_ELEMS + CV_ELEMS) * 4 / 16);
  prep_x<<<128, 256, 0, stream>>>(x, xT);
  prep_w<<<256, 256, 0, stream>>>(W2, W4, Wr);
  conv_gap<<<384, 256, 0, stream>>>(xT, Wr, convacc);
  reduce_gap<<<128, 256, 0, stream>>>(convacc, b2, b4, gapacc);
  dense_chain<<<2, 512, 0, stream>>>(gapacc, Wd, Wcc, bcc, Wd2, cvec);
  final_add<<<2048, 256, 0, stream>>>(x, cvec, out);
}

// Round 2
// 95.272 us; speedup vs baseline: 1.5030x; 1.5030x over previous
//
#include <hip/hip_runtime.h>
#include <hip/hip_bf16.h>

typedef short short8 __attribute__((ext_vector_type(8)));
typedef float f32x4 __attribute__((ext_vector_type(4)));
typedef unsigned short u16;

// ---------------- workspace layout (bytes) ----------------
// xTpad bf16 [2][78][78][512]  (x transposed to pos-major, halo 7, zero pad)
#define XT_ELEMS (2*78*78*512)
#define XT_OFF   0
// Wr bf16 [2 conv][9 tap][128 oc][512 c]
#define WR_ELEMS (2*9*128*512)
#define WR_OFF   (XT_OFF + XT_ELEMS*2)
// convacc fp32 [4 unit][4096 pos][128 oc]  (unit = conv*2 + b)
#define CA_ELEMS (4*4096*128)
#define CA_OFF   (WR_OFF + WR_ELEMS*2)
// gapacc fp32 [4 unit][128]
#define GA_ELEMS (4*128)
#define GA_OFF   (CA_OFF + CA_ELEMS*4)
// gv fp32 [4 combo][512]   (combo = b*2+br; br0 = o1-branch (gap4), br1 = o2-branch (gap2))
#define GV_ELEMS (4*512)
#define GV_OFF   (GA_OFF + GA_ELEMS*4)
// zv fp32 [4 combo][256]
#define ZV_ELEMS (4*256)
#define ZV_OFF   (GV_OFF + GV_ELEMS*4)
// cvec fp32 [2 b][512]
#define CV_ELEMS (2*512)
#define CV_OFF   (ZV_OFF + ZV_ELEMS*4)

// ---------------- zero fill ----------------
__global__ void zero_u4(uint4* __restrict__ p, int n) {
  int i = blockIdx.x * blockDim.x + threadIdx.x;
  int st = gridDim.x * blockDim.x;
  uint4 z = {0u, 0u, 0u, 0u};
  for (; i < n; i += st) p[i] = z;
}

// ---------------- x -> xTpad (fp32 NCHW -> bf16 [b][h+7][w+7][c]) ----------------
__global__ void prep_x(const float* __restrict__ x, u16* __restrict__ xT) {
  __shared__ float tile[64][65];
  int b = blockIdx.x >> 6, h = blockIdx.x & 63;
  int t = threadIdx.x;
  int w = t & 63, cq = t >> 6;   // load mapping
  int pi = t >> 2, q = t & 3;    // store mapping
  for (int cc = 0; cc < 8; ++cc) {
#pragma unroll
    for (int i = 0; i < 16; ++i) {
      int ci = cq + i * 4;
      tile[ci][w] = x[((b * 512 + cc * 64 + ci) * 4096) + h * 64 + w];
    }
    __syncthreads();
    union { u16 u[16]; uint4 v[2]; } pk;
#pragma unroll
    for (int k = 0; k < 16; ++k) {
      __hip_bfloat16 hb = __float2bfloat16(tile[q * 16 + k][pi]);
      pk.u[k] = *(u16*)&hb;
    }
    u16* dst = xT + ((size_t)(b * 78 + h + 7) * 78 + (pi + 7)) * 512 + cc * 64 + q * 16;
    *(uint4*)dst = pk.v[0];
    *(uint4*)(dst + 8) = pk.v[1];
    __syncthreads();
  }
}

// ---------------- W (OIHW fp32) -> Wr bf16 [conv][tap][oc][c] ----------------
__global__ void prep_w(const float* __restrict__ W2, const float* __restrict__ W4,
                       u16* __restrict__ Wr) {
  __shared__ float sw[4608];
  int conv = blockIdx.x >> 7, o = blockIdx.x & 127;
  const float* W = conv ? W4 : W2;
  int t = threadIdx.x;
#pragma unroll
  for (int k = 0; k < 18; ++k) sw[t * 18 + k] = W[o * 4608 + t * 18 + k];
  __syncthreads();
  for (int tap = 0; tap < 9; ++tap) {
    __hip_bfloat16 h0 = __float2bfloat16(sw[(2 * t) * 9 + tap]);
    __hip_bfloat16 h1 = __float2bfloat16(sw[(2 * t + 1) * 9 + tap]);
    unsigned int u = ((unsigned int)(*(u16*)&h1) << 16) | (unsigned int)(*(u16*)&h0);
    ((unsigned int*)(Wr + ((size_t)(conv * 9 + tap) * 128 + o) * 512))[t] = u;
  }
}

// ---------------- dilated conv partial sums via MFMA ----------------
// grid 384 = 64 groups(b,ptile) x {conv 2}x{kg 3}; WG tile: 128 pos x 128 oc, K = 3 taps x 512
__global__ __launch_bounds__(256) void conv_gap(
    const u16* __restrict__ xT, const u16* __restrict__ Wr,
    float* __restrict__ convacc) {
  __shared__ u16 lds[2][10240];  // per buf: A 128x40u16 (80B pitch) | B 128x40u16
  int bid = blockIdx.x;
  int g = bid / 6, r = bid % 6;
  int conv = r / 3, kg = r % 3;        // kg == kh
  int b = g >> 5, ptile = g & 31;
  int h0 = ptile * 2;
  int d = conv ? 7 : 3;
  int unit = conv * 2 + b;
  const u16* xb = xT + (size_t)b * 78 * 78 * 512;
  const u16* wb = Wr + (size_t)conv * 9 * 128 * 512;
  int t = threadIdx.x, lane = t & 63, wave = t >> 6;
  int wm = wave >> 1, wn = wave & 1;   // wave tile: pos [wm*64,+64), oc [wn*64,+64)
  int arow = t >> 1, slot = (t & 1) * 2;
  int hr = h0 + (arow >> 6), wq = arow & 63;
  int arowbase = ((hr + (kg - 1) * d + 7) * 78 + wq + 7) * 512;

  f32x4 acc[4][4];
#pragma unroll
  for (int i = 0; i < 4; ++i)
#pragma unroll
    for (int j = 0; j < 4; ++j) acc[i][j] = (f32x4){0.f, 0.f, 0.f, 0.f};

  uint4 ra0, ra1, rb0, rb1;
  auto load_s = [&](int s) {
    int tl = s >> 4, kc = s & 15;      // tap-local, k-chunk
    int c0 = kc * 32;
    int aoff = arowbase + ((tl - 1) * d) * 512 + c0 + slot * 8;
    ra0 = *(const uint4*)(xb + aoff);
    ra1 = *(const uint4*)(xb + aoff + 8);
    int tap = kg * 3 + tl;
    int boff = (tap * 128 + arow) * 512 + c0 + slot * 8;
    rb0 = *(const uint4*)(wb + boff);
    rb1 = *(const uint4*)(wb + boff + 8);
  };
  load_s(0);
  for (int s = 0; s < 48; ++s) {
    u16* L = lds[s & 1];
    *(uint4*)&L[arow * 40 + slot * 8] = ra0;
    *(uint4*)&L[arow * 40 + slot * 8 + 8] = ra1;
    *(uint4*)&L[5120 + arow * 40 + slot * 8] = rb0;
    *(uint4*)&L[5120 + arow * 40 + slot * 8 + 8] = rb1;
    if (s + 1 < 48) load_s(s + 1);
    __syncthreads();
    const u16* A = lds[s & 1];
    const u16* B = lds[s & 1] + 5120;
    short8 af[4], bf[4];
#pragma unroll
    for (int mi = 0; mi < 4; ++mi)
      af[mi] = *(const short8*)&A[(wm * 64 + mi * 16 + (lane & 15)) * 40 + (lane >> 4) * 8];
#pragma unroll
    for (int ni = 0; ni < 4; ++ni)
      bf[ni] = *(const short8*)&B[(wn * 64 + ni * 16 + (lane & 15)) * 40 + (lane >> 4) * 8];
#pragma unroll
    for (int mi = 0; mi < 4; ++mi)
#pragma unroll
      for (int ni = 0; ni < 4; ++ni)
        acc[mi][ni] = __builtin_amdgcn_mfma_f32_16x16x32_bf16(af[mi], bf[ni], acc[mi][ni], 0, 0, 0);
  }
  float* ca = convacc + (size_t)unit * 4096 * 128;
#pragma unroll
  for (int mi = 0; mi < 4; ++mi)
#pragma unroll
    for (int ni = 0; ni < 4; ++ni)
#pragma unroll
      for (int j = 0; j < 4; ++j) {
        int pos = h0 * 64 + wm * 64 + mi * 16 + (lane >> 4) * 4 + j;
        int oc = wn * 64 + ni * 16 + (lane & 15);
        atomicAdd(&ca[pos * 128 + oc], acc[mi][ni][j]);
      }
}

// ---------------- bias + relu + GAP ----------------
__global__ void reduce_gap(const float* __restrict__ convacc,
                           const float* __restrict__ b2, const float* __restrict__ b4,
                           float* __restrict__ gapacc) {
  int unit = blockIdx.x >> 5, chunk = blockIdx.x & 31;
  int conv = unit >> 1;
  const float* bias = conv ? b4 : b2;
  int t = threadIdx.x, oc = t & 127, half = t >> 7;
  const float* ca = convacc + (size_t)unit * 4096 * 128;
  float bi = bias[oc];
  float s = 0.f;
  for (int i = 0; i < 64; ++i) {
    int pos = chunk * 128 + half * 64 + i;
    float v = ca[pos * 128 + oc] + bi;
    s += v > 0.f ? v : 0.f;
  }
  __shared__ float red[2][128];
  red[half][oc] = s;
  __syncthreads();
  if (t < 128) atomicAdd(&gapacc[unit * 128 + t], red[0][t] + red[1][t]);
}

// ---------------- dense chain, stage 1: gv[combo][o] = Wd[o,:] . gap[combo] ----------------
// combo = b*2+br ; br0 -> gap4 (unit 2+b), br1 -> gap2 (unit b). grid 512, block 128.
__global__ void dense1(const float* __restrict__ gapacc, const float* __restrict__ Wd,
                       float* __restrict__ gv) {
  int o = blockIdx.x, t = threadIdx.x;
  float w = Wd[o * 128 + t];
  float p0 = w * gapacc[2 * 128 + t];  // b0, br0 (gap4)
  float p1 = w * gapacc[0 * 128 + t];  // b0, br1 (gap2)
  float p2 = w * gapacc[3 * 128 + t];  // b1, br0
  float p3 = w * gapacc[1 * 128 + t];  // b1, br1
#pragma unroll
  for (int m = 1; m < 64; m <<= 1) {
    p0 += __shfl_xor(p0, m);
    p1 += __shfl_xor(p1, m);
    p2 += __shfl_xor(p2, m);
    p3 += __shfl_xor(p3, m);
  }
  __shared__ float red[2][4];
  if ((t & 63) == 0) {
    red[t >> 6][0] = p0; red[t >> 6][1] = p1;
    red[t >> 6][2] = p2; red[t >> 6][3] = p3;
  }
  __syncthreads();
  if (t < 4) {
    const float inv = 1.f / 4096.f;
    gv[t * 512 + o] = (red[0][t] + red[1][t]) * inv;
  }
}

// ---------------- stage 2: zv[combo][o] = bcc[o] + Wcc[o,:] . gv[combo] ----------------
// grid 256, block 256.
__global__ void dense2(const float* __restrict__ gv, const float* __restrict__ Wcc,
                       const float* __restrict__ bcc, float* __restrict__ zv) {
  int o = blockIdx.x, t = threadIdx.x;
  float w0 = Wcc[o * 512 + t], w1 = Wcc[o * 512 + 256 + t];
  float p[4];
#pragma unroll
  for (int c = 0; c < 4; ++c)
    p[c] = w0 * gv[c * 512 + t] + w1 * gv[c * 512 + 256 + t];
#pragma unroll
  for (int m = 1; m < 64; m <<= 1)
#pragma unroll
    for (int c = 0; c < 4; ++c) p[c] += __shfl_xor(p[c], m);
  __shared__ float red[4][4];
  if ((t & 63) == 0)
#pragma unroll
    for (int c = 0; c < 4; ++c) red[t >> 6][c] = p[c];
  __syncthreads();
  if (t < 4) {
    float s = bcc[o];
#pragma unroll
    for (int wv = 0; wv < 4; ++wv) s += red[wv][t];
    zv[t * 256 + o] = s;
  }
}

// ---------------- stage 3: cvec[b][o] = Wd2[o,:] . (zv[b*2] + zv[b*2+1]) ----------------
// grid 512, block 256.
__global__ void dense3(const float* __restrict__ zv, const float* __restrict__ Wd2,
                       float* __restrict__ cvec) {
  int o = blockIdx.x, t = threadIdx.x;
  float w = Wd2[o * 256 + t];
  float p0 = w * (zv[0 * 256 + t] + zv[1 * 256 + t]);  // b0
  float p1 = w * (zv[2 * 256 + t] + zv[3 * 256 + t]);  // b1
#pragma unroll
  for (int m = 1; m < 64; m <<= 1) {
    p0 += __shfl_xor(p0, m);
    p1 += __shfl_xor(p1, m);
  }
  __shared__ float red[4][2];
  if ((t & 63) == 0) { red[t >> 6][0] = p0; red[t >> 6][1] = p1; }
  __syncthreads();
  if (t < 2) {
    float s = red[0][t] + red[1][t] + red[2][t] + red[3][t];
    cvec[t * 512 + o] = s;
  }
}

// ---------------- out = x + cvec[b][ch] ----------------
__global__ void final_add(const float* __restrict__ x, const float* __restrict__ cvec,
                          float* __restrict__ out) {
  int i = blockIdx.x * blockDim.x + threadIdx.x;
  int st = gridDim.x * blockDim.x;
  const float4* x4 = (const float4*)x;
  float4* o4 = (float4*)out;
  for (; i < 1048576; i += st) {
    int flat = i << 2;
    int b = flat >> 21;
    int ch = (flat >> 12) & 511;
    float c = cvec[b * 512 + ch];
    float4 v = x4[i];
    v.x += c; v.y += c; v.z += c; v.w += c;
    o4[i] = v;
  }
}

extern "C" void kernel_launch(void* const* d_in, const int* in_sizes, int n_in,
                              void* d_out, int out_size, void* d_ws, size_t ws_size,
                              hipStream_t stream) {
  const float* x   = (const float*)d_in[0];
  const float* W2  = (const float*)d_in[3];
  const float* b2  = (const float*)d_in[4];
  const float* W4  = (const float*)d_in[7];
  const float* b4  = (const float*)d_in[8];
  const float* Wd  = (const float*)d_in[9];
  const float* Wcc = (const float*)d_in[10];
  const float* bcc = (const float*)d_in[11];
  const float* Wd2 = (const float*)d_in[12];
  float* out = (float*)d_out;

  char* ws = (char*)d_ws;
  u16*   xT      = (u16*)(ws + XT_OFF);
  u16*   Wr      = (u16*)(ws + WR_OFF);
  float* convacc = (float*)(ws + CA_OFF);
  float* gapacc  = (float*)(ws + GA_OFF);
  float* gv      = (float*)(ws + GV_OFF);
  float* zv      = (float*)(ws + ZV_OFF);
  float* cvec    = (float*)(ws + CV_OFF);

  // zero xTpad (halo stays 0) and the atomic accumulators (convacc + gapacc, contiguous)
  zero_u4<<<512, 256, 0, stream>>>((uint4*)xT, XT_ELEMS * 2 / 16);
  zero_u4<<<512, 256, 0, stream>>>((uint4*)convacc, (CA_ELEMS + GA_ELEMS) * 4 / 16);
  prep_x<<<128, 256, 0, stream>>>(x, xT);
  prep_w<<<256, 256, 0, stream>>>(W2, W4, Wr);
  conv_gap<<<384, 256, 0, stream>>>(xT, Wr, convacc);
  reduce_gap<<<128, 256, 0, stream>>>(convacc, b2, b4, gapacc);
  dense1<<<512, 128, 0, stream>>>(gapacc, Wd, gv);
  dense2<<<256, 256, 0, stream>>>(gv, Wcc, bcc, zv);
  dense3<<<512, 256, 0, stream>>>(zv, Wd2, cvec);
  final_add<<<2048, 256, 0, stream>>>(x, cvec, out);
}

// Round 3
// 68.092 us; speedup vs baseline: 2.1029x; 1.3992x over previous
//
#include <hip/hip_runtime.h>
#include <hip/hip_bf16.h>

typedef short short8 __attribute__((ext_vector_type(8)));
typedef float f32x4 __attribute__((ext_vector_type(4)));
typedef unsigned short u16;

// ---------------- workspace layout (bytes) ----------------
// xTpad bf16 [2][78][78][512]
#define XT_OFF   0
#define XT_BYTES (2*78*78*512*2)                  // 12,460,032
// Wr2 bf16 frag-packed: [conv2][tap9][kc16][wn2][ni4][lane64][8elem]
#define WR2_OFF  (XT_OFF + XT_BYTES)
#define WR2_BYTES (2*9*16*8*64*16)                // 2,359,296
#define AFTER_W  (WR2_OFF + WR2_BYTES)            // 14,819,328
// --- partial-store path ---
#define P_OFF    AFTER_W
#define P_BYTES  (4*4*4096*128*2)                 // 16,777,216 (bf16)
#define GA_OFF_P (P_OFF + P_BYTES)                // 31,596,544
// --- atomic fallback path ---
#define CA_OFF   AFTER_W
#define CA_BYTES (4*4096*128*4)                   // 8,388,608 (fp32)
#define GA_OFF_A (CA_OFF + CA_BYTES)              // 23,207,936
// tails (relative to GA_OFF_x)
#define GA_BYTES 2048
#define GV_REL   GA_BYTES
#define ZV_REL   (GV_REL + 4*512*4)
#define CV_REL   (ZV_REL + 4*256*4)
#define TAIL_END (CV_REL + 2*512*4)
#define WS_NEED_P ((size_t)GA_OFF_P + TAIL_END)   // 31,614,976
#define WS_NEED_A ((size_t)GA_OFF_A + TAIL_END)   // 23,226,368 (proven to fit)

static __device__ __forceinline__ void async_cp16(u16* lds, const u16* g) {
  __builtin_amdgcn_global_load_lds(
      (const __attribute__((address_space(1))) void*)g,
      (__attribute__((address_space(3))) void*)lds, 16, 0, 0);
}

// ---------------- zero fill ----------------
__global__ void zero_u4(uint4* __restrict__ p, int n) {
  int i = blockIdx.x * blockDim.x + threadIdx.x;
  int st = gridDim.x * blockDim.x;
  uint4 z = {0u, 0u, 0u, 0u};
  for (; i < n; i += st) p[i] = z;
}

// zero only the halo of xTpad (interior is fully written by prep_x)
__global__ void zero_halo(u16* __restrict__ xT) {
  int bid = blockIdx.x;
  size_t off; int cnt;
  if (bid < 256) {  // w-strips: h in [7,71), w in [0,7) or [71,78)
    int b = bid >> 7, rem = bid & 127, h = rem >> 1, side = rem & 1;
    off = ((size_t)(b * 78 + 7 + h) * 78 + (side ? 71 : 0)) * 512;
    cnt = 7 * 512;
  } else {          // h-spans: rows [0,7) and [71,78), full width, 8 chunks each
    int k = bid - 256;
    int b = k >> 4, topbot = (k >> 3) & 1, ch = k & 7;
    off = ((size_t)b * 78 + (topbot ? 71 : 0)) * 78 * 512 + (size_t)ch * 34944;
    cnt = 34944;
  }
  uint4* p = (uint4*)(xT + off);
  int n = cnt >> 3;
  uint4 z = {0u, 0u, 0u, 0u};
  for (int i = threadIdx.x; i < n; i += blockDim.x) p[i] = z;
}

// ---------------- x -> xTpad (fp32 NCHW -> bf16 [b][h+7][w+7][c]) ----------------
__global__ void prep_x(const float* __restrict__ x, u16* __restrict__ xT) {
  __shared__ float tile[64][65];
  int bh = blockIdx.x >> 3, cc = blockIdx.x & 7;
  int b = bh >> 6, h = bh & 63;
  int t = threadIdx.x;
  int w = t & 63, cq4 = t >> 6;
  int pi = t >> 2, q = t & 3;
#pragma unroll
  for (int i = 0; i < 16; ++i) {
    int ci = cq4 + i * 4;
    tile[ci][w] = x[((b * 512 + cc * 64 + ci) * 4096) + h * 64 + w];
  }
  __syncthreads();
  union { u16 u[16]; uint4 v[2]; } pk;
#pragma unroll
  for (int k = 0; k < 16; ++k) {
    __hip_bfloat16 hb = __float2bfloat16(tile[q * 16 + k][pi]);
    pk.u[k] = *(u16*)&hb;
  }
  u16* dst = xT + ((size_t)(b * 78 + h + 7) * 78 + (pi + 7)) * 512 + cc * 64 + q * 16;
  *(uint4*)dst = pk.v[0];
  *(uint4*)(dst + 8) = pk.v[1];
}

// ---------------- W (OIHW fp32) -> Wr2 frag-packed bf16 ----------------
// Wr2[conv][(tap*16+kc)*8 + wn*4 + ni][lane][e]: oc=wn*64+ni*16+(lane&15), c=kc*32+(lane>>4)*8+e
__global__ void prep_w2(const float* __restrict__ W2, const float* __restrict__ W4,
                        u16* __restrict__ Wr2) {
  int bid = blockIdx.x;                 // 288 = 2 conv * 9 tap * 16 kc
  int conv = bid / 144, rem = bid % 144;
  int tap = rem >> 4, kc = rem & 15;
  const float* W = conv ? W4 : W2;
  u16* dst = Wr2 + (size_t)conv * (9*16*8*64*8) + (size_t)(tap * 16 + kc) * 4096;
  int t = threadIdx.x;
#pragma unroll
  for (int rep = 0; rep < 2; ++rep) {
    int u = t + rep * 256;
    int wn = u >> 8, ni = (u >> 6) & 3, l = u & 63;
    int oc = wn * 64 + ni * 16 + (l & 15);
    int c = kc * 32 + (l >> 4) * 8;
    union { u16 h[8]; uint4 v[2]; } pk;
#pragma unroll
    for (int e = 0; e < 8; ++e) {
      __hip_bfloat16 hb = __float2bfloat16(W[(size_t)(oc * 512 + c + e) * 9 + tap]);
      pk.h[e] = *(u16*)&hb;
    }
    *(uint4*)(dst + (size_t)u * 8) = pk.v[0];
    *(uint4*)(dst + (size_t)u * 8 + 4) = ((uint4*)&pk)[1];
  }
}

// ---------------- dilated conv via MFMA ----------------
// grid 512 = [u 4][ptile 32][cq 4]; tile 128pos x 128oc; K/block = 9 taps x 128c (c-quarter)
// A: global_load_lds staged (pre-swizzled source, linear LDS); B: direct global frag loads.
template<int MODE>  // 0 = bf16 partial stores, 1 = fp32 atomicAdd into convacc
__global__ __launch_bounds__(256, 2) void conv_mfma(
    const u16* __restrict__ xT, const u16* __restrict__ Wr2,
    u16* __restrict__ Pp, float* __restrict__ convacc) {
  __shared__ __align__(16) u16 Ab[2][4096];     // 2 x 8KB: 128 rows x 64B
  int bid = blockIdx.x;
  int cq = bid & 3, pt = (bid >> 2) & 31, u = bid >> 7;
  int b = u & 1, conv = u >> 1;
  int d = conv ? 7 : 3;
  int h0 = pt * 2;
  const u16* xb = xT + (size_t)b * (78 * 78 * 512);
  int t = threadIdx.x, l = t & 63, wv = t >> 6;
  int wm = wv >> 1, wn = wv & 1;

  // --- staging geometry: thread covers LDS rows r = i*64 + wv*16 + (l>>2), phys slot p = l&3
  int w = wv * 16 + (l >> 2);
  int qs = ((l >> 2) & 3) ^ ((l >> 4) & 1);     // = q(r) for this thread's rows
  int slog = (l & 3) ^ qs;                      // logical 16B slot to fetch
  const char* gA0 = (const char*)(xb + ((size_t)(h0 + 0 - d + 7) * 78 + (w - d + 7)) * 512
                                  + cq * 128 + slog * 8);
  const char* gA1 = (const char*)(xb + ((size_t)(h0 + 1 - d + 7) * 78 + (w - d + 7)) * 512
                                  + cq * 128 + slog * 8);
  const char* bB = (const char*)Wr2 + (size_t)conv * 1179648
                   + (size_t)(cq * 32 + wn * 4) * 1024 + l * 16;

  // --- reader swizzle: row r = wm*64+mi*16+(l&15); phys slot = (l>>4) ^ q(r)
  int qr = (l & 3) ^ ((l >> 2) & 1);
  int rd_off = (l & 15) * 32 + (((l >> 4) ^ qr) & 3) * 8;   // u16 units

  f32x4 acc[4][4];
#pragma unroll
  for (int i = 0; i < 4; ++i)
#pragma unroll
    for (int j = 0; j < 4; ++j) acc[i][j] = (f32x4){0.f, 0.f, 0.f, 0.f};

  short8 bf0[4], bf1[4];

  auto issueA = [&](int buf) {
    async_cp16(&Ab[buf][wv * 512], (const u16*)gA0);
    async_cp16(&Ab[buf][2048 + wv * 512], (const u16*)gA1);
  };
  auto loadB = [&](short8* bf) {
    bf[0] = *(const short8*)(bB);
    bf[1] = *(const short8*)(bB + 1024);
    bf[2] = *(const short8*)(bB + 2048);
    bf[3] = *(const short8*)(bB + 3072);
  };
  auto advance = [&](int sl) {    // move pointers from step sl to sl+1
    int nk = sl + 1;
    int dA, dB;
    if (nk & 3) { dA = 64; dB = 8192; }
    else {
      dB = 106496;                 // 13*8192: skip to next tap, back to this c-quarter
      int tap = nk >> 2;
      dA = (tap % 3) ? (1024 * d - 192) : (77824 * d - 192);
    }
    gA0 += dA; gA1 += dA; bB += dB;
  };
  auto compute = [&](int buf, short8* bf) {
    const u16* A = Ab[buf];
    short8 af[4];
#pragma unroll
    for (int mi = 0; mi < 4; ++mi)
      af[mi] = *(const short8*)&A[wm * 2048 + mi * 512 + rd_off];
#pragma unroll
    for (int mi = 0; mi < 4; ++mi)
#pragma unroll
      for (int ni = 0; ni < 4; ++ni)
        acc[mi][ni] = __builtin_amdgcn_mfma_f32_16x16x32_bf16(af[mi], bf[ni], acc[mi][ni], 0, 0, 0);
  };

  issueA(0); loadB(bf0); advance(0);
  __syncthreads();
  for (int it = 0; it < 18; ++it) {
    int s = it * 2;
    issueA(1); loadB(bf1); advance(s + 1);
    compute(0, bf0);
    __syncthreads();
    if (it < 17) { issueA(0); loadB(bf0); advance(s + 2); }
    compute(1, bf1);
    __syncthreads();
  }

  if (MODE == 0) {
    // bf16 partial store: P[cq][u][pos][oc]
    u16* PP = Pp + ((size_t)(cq * 4 + u) * 4096 + pt * 128 + wm * 64 + (l >> 4) * 4) * 128
              + wn * 64 + (l & 15);
#pragma unroll
    for (int mi = 0; mi < 4; ++mi)
#pragma unroll
      for (int ni = 0; ni < 4; ++ni)
#pragma unroll
        for (int j = 0; j < 4; ++j) {
          __hip_bfloat16 hv = __float2bfloat16(acc[mi][ni][j]);
          PP[(mi * 16 + j) * 128 + ni * 16] = *(u16*)&hv;
        }
  } else {
    float* ca = convacc + (size_t)u * 4096 * 128;
#pragma unroll
    for (int mi = 0; mi < 4; ++mi)
#pragma unroll
      for (int ni = 0; ni < 4; ++ni)
#pragma unroll
        for (int j = 0; j < 4; ++j) {
          int pos = pt * 128 + wm * 64 + mi * 16 + (l >> 4) * 4 + j;
          int oc = wn * 64 + ni * 16 + (l & 15);
          atomicAdd(&ca[pos * 128 + oc], acc[mi][ni][j]);
        }
  }
}

// ---------------- bias + relu + GAP (partial path) ----------------
__global__ void reduce_gap_p(const u16* __restrict__ P,
                             const float* __restrict__ b2, const float* __restrict__ b4,
                             float* __restrict__ gapacc) {
  int u = blockIdx.x >> 7, chunk = blockIdx.x & 127;   // 4 units x 128 chunks (32 pos)
  int conv = u >> 1;
  const float* bias = conv ? b4 : b2;
  int t = threadIdx.x, oc = t & 127, half = t >> 7;
  float bi = bias[oc], s = 0.f;
  for (int i = 0; i < 16; ++i) {
    int pos = chunk * 32 + half * 16 + i;
    size_t base = ((size_t)u * 4096 + pos) * 128 + oc;
    float v = bi;
#pragma unroll
    for (int cq = 0; cq < 4; ++cq)
      v += __builtin_bit_cast(float, (unsigned)P[base + (size_t)cq * 2097152] << 16);
    s += v > 0.f ? v : 0.f;
  }
  __shared__ float red[2][128];
  red[half][oc] = s;
  __syncthreads();
  if (t < 128) atomicAdd(&gapacc[u * 128 + t], red[0][t] + red[1][t]);
}

// ---------------- bias + relu + GAP (atomic fallback path) ----------------
__global__ void reduce_gap_a(const float* __restrict__ convacc,
                             const float* __restrict__ b2, const float* __restrict__ b4,
                             float* __restrict__ gapacc) {
  int unit = blockIdx.x >> 5, chunk = blockIdx.x & 31;
  int conv = unit >> 1;
  const float* bias = conv ? b4 : b2;
  int t = threadIdx.x, oc = t & 127, half = t >> 7;
  const float* ca = convacc + (size_t)unit * 4096 * 128;
  float bi = bias[oc];
  float s = 0.f;
  for (int i = 0; i < 64; ++i) {
    int pos = chunk * 128 + half * 64 + i;
    float v = ca[pos * 128 + oc] + bi;
    s += v > 0.f ? v : 0.f;
  }
  __shared__ float red[2][128];
  red[half][oc] = s;
  __syncthreads();
  if (t < 128) atomicAdd(&gapacc[unit * 128 + t], red[0][t] + red[1][t]);
}

// ---------------- dense chain ----------------
__global__ void dense1(const float* __restrict__ gapacc, const float* __restrict__ Wd,
                       float* __restrict__ gv) {
  int o = blockIdx.x, t = threadIdx.x;
  float w = Wd[o * 128 + t];
  float p0 = w * gapacc[2 * 128 + t];
  float p1 = w * gapacc[0 * 128 + t];
  float p2 = w * gapacc[3 * 128 + t];
  float p3 = w * gapacc[1 * 128 + t];
#pragma unroll
  for (int m = 1; m < 64; m <<= 1) {
    p0 += __shfl_xor(p0, m); p1 += __shfl_xor(p1, m);
    p2 += __shfl_xor(p2, m); p3 += __shfl_xor(p3, m);
  }
  __shared__ float red[2][4];
  if ((t & 63) == 0) {
    red[t >> 6][0] = p0; red[t >> 6][1] = p1;
    red[t >> 6][2] = p2; red[t >> 6][3] = p3;
  }
  __syncthreads();
  if (t < 4) {
    const float inv = 1.f / 4096.f;
    gv[t * 512 + o] = (red[0][t] + red[1][t]) * inv;
  }
}

__global__ void dense2(const float* __restrict__ gv, const float* __restrict__ Wcc,
                       const float* __restrict__ bcc, float* __restrict__ zv) {
  int o = blockIdx.x, t = threadIdx.x;
  float w0 = Wcc[o * 512 + t], w1 = Wcc[o * 512 + 256 + t];
  float p[4];
#pragma unroll
  for (int c = 0; c < 4; ++c)
    p[c] = w0 * gv[c * 512 + t] + w1 * gv[c * 512 + 256 + t];
#pragma unroll
  for (int m = 1; m < 64; m <<= 1)
#pragma unroll
    for (int c = 0; c < 4; ++c) p[c] += __shfl_xor(p[c], m);
  __shared__ float red[4][4];
  if ((t & 63) == 0)
#pragma unroll
    for (int c = 0; c < 4; ++c) red[t >> 6][c] = p[c];
  __syncthreads();
  if (t < 4) {
    float s = bcc[o];
#pragma unroll
    for (int wv = 0; wv < 4; ++wv) s += red[wv][t];
    zv[t * 256 + o] = s;
  }
}

__global__ void dense3(const float* __restrict__ zv, const float* __restrict__ Wd2,
                       float* __restrict__ cvec) {
  int o = blockIdx.x, t = threadIdx.x;
  float w = Wd2[o * 256 + t];
  float p0 = w * (zv[0 * 256 + t] + zv[1 * 256 + t]);
  float p1 = w * (zv[2 * 256 + t] + zv[3 * 256 + t]);
#pragma unroll
  for (int m = 1; m < 64; m <<= 1) {
    p0 += __shfl_xor(p0, m);
    p1 += __shfl_xor(p1, m);
  }
  __shared__ float red[4][2];
  if ((t & 63) == 0) { red[t >> 6][0] = p0; red[t >> 6][1] = p1; }
  __syncthreads();
  if (t < 2) {
    float s = red[0][t] + red[1][t] + red[2][t] + red[3][t];
    cvec[t * 512 + o] = s;
  }
}

// ---------------- out = x + cvec[b][ch] ----------------
__global__ void final_add(const float* __restrict__ x, const float* __restrict__ cvec,
                          float* __restrict__ out) {
  int i = blockIdx.x * blockDim.x + threadIdx.x;
  int st = gridDim.x * blockDim.x;
  const float4* x4 = (const float4*)x;
  float4* o4 = (float4*)out;
  for (; i < 1048576; i += st) {
    int flat = i << 2;
    int b = flat >> 21;
    int ch = (flat >> 12) & 511;
    float c = cvec[b * 512 + ch];
    float4 v = x4[i];
    v.x += c; v.y += c; v.z += c; v.w += c;
    o4[i] = v;
  }
}

extern "C" void kernel_launch(void* const* d_in, const int* in_sizes, int n_in,
                              void* d_out, int out_size, void* d_ws, size_t ws_size,
                              hipStream_t stream) {
  const float* x   = (const float*)d_in[0];
  const float* W2  = (const float*)d_in[3];
  const float* b2  = (const float*)d_in[4];
  const float* W4  = (const float*)d_in[7];
  const float* b4  = (const float*)d_in[8];
  const float* Wd  = (const float*)d_in[9];
  const float* Wcc = (const float*)d_in[10];
  const float* bcc = (const float*)d_in[11];
  const float* Wd2 = (const float*)d_in[12];
  float* out = (float*)d_out;

  char* ws = (char*)d_ws;
  u16* xT  = (u16*)(ws + XT_OFF);
  u16* Wr2 = (u16*)(ws + WR2_OFF);

  const bool partial = ws_size >= WS_NEED_P;
  size_t ga_off = partial ? GA_OFF_P : GA_OFF_A;
  float* gapacc = (float*)(ws + ga_off);
  float* gv     = (float*)(ws + ga_off + GV_REL);
  float* zv     = (float*)(ws + ga_off + ZV_REL);
  float* cvec   = (float*)(ws + ga_off + CV_REL);

  zero_halo<<<288, 256, 0, stream>>>(xT);
  prep_x<<<1024, 256, 0, stream>>>(x, xT);
  prep_w2<<<288, 256, 0, stream>>>(W2, W4, Wr2);

  if (partial) {
    u16* Pp = (u16*)(ws + P_OFF);
    zero_u4<<<1, 256, 0, stream>>>((uint4*)gapacc, GA_BYTES / 16);
    conv_mfma<0><<<512, 256, 0, stream>>>(xT, Wr2, Pp, nullptr);
    reduce_gap_p<<<512, 256, 0, stream>>>(Pp, b2, b4, gapacc);
  } else {
    float* convacc = (float*)(ws + CA_OFF);
    zero_u4<<<512, 256, 0, stream>>>((uint4*)convacc, (CA_BYTES + GA_BYTES) / 16);
    conv_mfma<1><<<512, 256, 0, stream>>>(xT, Wr2, nullptr, convacc);
    reduce_gap_a<<<128, 256, 0, stream>>>(convacc, b2, b4, gapacc);
  }

  dense1<<<512, 128, 0, stream>>>(gapacc, Wd, gv);
  dense2<<<256, 256, 0, stream>>>(gv, Wcc, bcc, zv);
  dense3<<<512, 256, 0, stream>>>(zv, Wd2, cvec);
  final_add<<<2048, 256, 0, stream>>>(x, cvec, out);
}

// Round 5
// 58.668 us; speedup vs baseline: 2.4407x; 1.1606x over previous
//
#include <hip/hip_runtime.h>
#include <hip/hip_bf16.h>

typedef short short8 __attribute__((ext_vector_type(8)));
typedef float f32x4 __attribute__((ext_vector_type(4)));
typedef unsigned short u16;

// ---------------- workspace layout (bytes) ----------------
#define XT_OFF   0
#define XT_BYTES (2*78*78*512*2)                  // 12,460,032
#define WR2_OFF  (XT_OFF + XT_BYTES)
#define WR2_BYTES (2*9*16*8*64*16)                // 2,359,296
#define AFTER_W  (WR2_OFF + WR2_BYTES)            // 14,819,328
// --- partial-store path ---
#define P_OFF    AFTER_W
#define P_BYTES  (4*4*4096*128*2)                 // 16,777,216 (bf16)
#define GA_OFF_P (P_OFF + P_BYTES)
// --- atomic fallback path ---
#define CA_OFF   AFTER_W
#define CA_BYTES (4*4096*128*4)
#define GA_OFF_A (CA_OFF + CA_BYTES)
#define GA_BYTES 2048
#define GV_REL   GA_BYTES
#define ZV_REL   (GV_REL + 4*512*4)
#define CV_REL   (ZV_REL + 4*256*4)
#define TAIL_END (CV_REL + 2*512*4)
#define WS_NEED_P ((size_t)GA_OFF_P + TAIL_END)
#define WS_NEED_A ((size_t)GA_OFF_A + TAIL_END)

static __device__ __forceinline__ void async_cp16(u16* lds, const u16* g) {
  __builtin_amdgcn_global_load_lds(
      (const __attribute__((address_space(1))) void*)g,
      (__attribute__((address_space(3))) void*)lds, 16, 0, 0);
}

// ---------------- zero fill (fallback path only) ----------------
__global__ void zero_u4(uint4* __restrict__ p, int n) {
  int i = blockIdx.x * blockDim.x + threadIdx.x;
  int st = gridDim.x * blockDim.x;
  uint4 z = {0u, 0u, 0u, 0u};
  for (; i < n; i += st) p[i] = z;
}

// ---------------- prep_misc: halo zero (0..287) | W pack (288..543) | gapacc zero (544) ----
__global__ void prep_misc(u16* __restrict__ xT,
                          const float* __restrict__ W2, const float* __restrict__ W4,
                          u16* __restrict__ Wr2, float* __restrict__ gapacc) {
  int bid = blockIdx.x;
  int t = threadIdx.x;
  if (bid < 288) {
    size_t off; int cnt;
    if (bid < 256) {  // w-strips: h in [7,71), w in [0,7) or [71,78)
      int b = bid >> 7, rem = bid & 127, h = rem >> 1, side = rem & 1;
      off = ((size_t)(b * 78 + 7 + h) * 78 + (side ? 71 : 0)) * 512;
      cnt = 7 * 512;
    } else {          // h-spans: rows [0,7) and [71,78)
      int k = bid - 256;
      int b = k >> 4, topbot = (k >> 3) & 1, ch = k & 7;
      off = ((size_t)b * 78 + (topbot ? 71 : 0)) * 78 * 512 + (size_t)ch * 34944;
      cnt = 34944;
    }
    uint4* p = (uint4*)(xT + off);
    int n = cnt >> 3;
    uint4 z = {0u, 0u, 0u, 0u};
    for (int i = t; i < n; i += blockDim.x) p[i] = z;
  } else if (bid < 544) {
    // coalesced W pack: one block per (conv, oc)
    int idx = bid - 288;
    int conv = idx >> 7, o = idx & 127;
    const float* W = conv ? W4 : W2;
    __shared__ float sw[4608];
    const float* src = W + (size_t)o * 4608;
    for (int k = 0; k < 18; ++k) sw[t + k * 256] = src[t + k * 256];
    __syncthreads();
    if (t < 144) {
      int tap = t >> 4, kc = t & 15;
      int wn = o >> 6, ni = (o >> 4) & 3;
      size_t base = (size_t)conv * 589824 + (size_t)(tap * 16 + kc) * 4096
                    + (wn * 4 + ni) * 512;
#pragma unroll
      for (int cg = 0; cg < 4; ++cg) {
        union { u16 h[8]; uint4 v; } pk;
#pragma unroll
        for (int e = 0; e < 8; ++e) {
          __hip_bfloat16 hb = __float2bfloat16(sw[(kc * 32 + cg * 8 + e) * 9 + tap]);
          pk.h[e] = *(u16*)&hb;
        }
        int lane = cg * 16 + (o & 15);
        *(uint4*)(Wr2 + base + lane * 8) = pk.v;
      }
    }
  } else {
    // FIX (round 4 bug): block has 256 threads, gapacc has 512 floats —
    // the old `if (t < 512) gapacc[t] = 0` left units 2,3 un-zeroed, so
    // reduce's atomicAdds accumulated across graph replays.
    gapacc[t] = 0.f;
    gapacc[t + 256] = 0.f;
  }
}

// ---------------- x -> xTpad (fp32 NCHW -> bf16 [b][h+7][w+7][c]) ----------------
__global__ void prep_x(const float* __restrict__ x, u16* __restrict__ xT) {
  __shared__ float tile[64][65];
  int bh = blockIdx.x >> 3, cc = blockIdx.x & 7;
  int b = bh >> 6, h = bh & 63;
  int t = threadIdx.x;
  int w = t & 63, cq4 = t >> 6;
  int pi = t >> 2, q = t & 3;
#pragma unroll
  for (int i = 0; i < 16; ++i) {
    int ci = cq4 + i * 4;
    tile[ci][w] = x[((b * 512 + cc * 64 + ci) * 4096) + h * 64 + w];
  }
  __syncthreads();
  union { u16 u[16]; uint4 v[2]; } pk;
#pragma unroll
  for (int k = 0; k < 16; ++k) {
    __hip_bfloat16 hb = __float2bfloat16(tile[q * 16 + k][pi]);
    pk.u[k] = *(u16*)&hb;
  }
  u16* dst = xT + ((size_t)(b * 78 + h + 7) * 78 + (pi + 7)) * 512 + cc * 64 + q * 16;
  *(uint4*)dst = pk.v[0];
  *(uint4*)(dst + 8) = pk.v[1];
}

// ---------------- dilated conv via MFMA, BK=64, XCD-sibling-mapped ----------------
// decode: xcd=bid&7, j=bid>>3, cq=j&3, g=j>>2, u=g>>2, pt=(g&3)*8+xcd
// tile 128pos x 128oc; per block K = 9 taps x 128c (c-quarter); 18 steps of BK=64.
// LDS: 2 bufs x 128 rows x 128B; 16B-slot swizzle phys = logical ^ (row&7).
template<int MODE>
__global__ __launch_bounds__(256, 2) void conv_mfma(
    const u16* __restrict__ xT, const u16* __restrict__ Wr2,
    u16* __restrict__ Pp, float* __restrict__ convacc) {
  __shared__ __align__(16) u16 Ab[2][8192];     // 2 x 16KB
  int bid = blockIdx.x;
  int xcd = bid & 7, j = bid >> 3, g = j >> 2, cq = j & 3;
  int u = g >> 2, pt = (g & 3) * 8 + xcd;
  int b = u & 1, conv = u >> 1;
  int d = conv ? 7 : 3;
  int h0 = pt * 2;
  const u16* xb = xT + (size_t)b * (78 * 78 * 512);
  int t = threadIdx.x, l = t & 63, wv = t >> 6;
  int wm = wv >> 1, wn = wv & 1;

  // staging: call m (=hh*2+mh) covers rows m*32 + wv*8 + (l>>3); lane writes phys slot l&7
  // logical slot needed there: (l&7) ^ (row&7) = (l&7) ^ (l>>3)
  int slog = (l & 7) ^ (l >> 3);
  int wq = wv * 8 + (l >> 3);                    // w within half
  const u16* gA[4];
#pragma unroll
  for (int m = 0; m < 4; ++m) {
    int hh = m >> 1, mh = m & 1;
    gA[m] = xb + ((size_t)(h0 + hh - d + 7) * 78 + (mh * 32 + wq - d + 7)) * 512
            + cq * 128 + slog * 8;
  }
  const char* bB = (const char*)Wr2 + (size_t)conv * 1179648
                   + cq * 32768 + wn * 4096 + l * 16;

  // reader: row r = wm*64+mi*16+(l&15); logical slot c01*4+(l>>4); phys ^= (l&7)
  int rbase = (wm * 64 + (l & 15)) * 64;
  int rs0 = (((l >> 4)) ^ (l & 7)) * 8;
  int rs1 = ((4 + (l >> 4)) ^ (l & 7)) * 8;

  f32x4 acc[4][4];
#pragma unroll
  for (int i = 0; i < 4; ++i)
#pragma unroll
    for (int jj = 0; jj < 4; ++jj) acc[i][jj] = (f32x4){0.f, 0.f, 0.f, 0.f};

  short8 bf0[2][4], bf1[2][4];

  auto issueA = [&](int buf) {
#pragma unroll
    for (int m = 0; m < 4; ++m)
      async_cp16(&Ab[buf][m * 2048 + wv * 512], gA[m]);
  };
  auto loadB = [&](short8 bf[2][4]) {
#pragma unroll
    for (int c01 = 0; c01 < 2; ++c01)
#pragma unroll
      for (int ni = 0; ni < 4; ++ni)
        bf[c01][ni] = *(const short8*)(bB + c01 * 8192 + ni * 1024);
  };
  auto advance = [&](int s) {     // pointers: step s -> s+1
    int dA, dB;
    if (!(s & 1)) { dA = 64; dB = 16384; }       // u16 / bytes
    else {
      dB = 114688;
      int tap = (s + 1) >> 1;
      dA = (tap % 3) ? (512 * d - 64) : (38912 * d - 64);   // u16
    }
#pragma unroll
    for (int m = 0; m < 4; ++m) gA[m] += dA;
    bB += dB;
  };
  auto compute = [&](int buf, short8 bf[2][4]) {
    const u16* A = Ab[buf];
    short8 af[2][4];
#pragma unroll
    for (int mi = 0; mi < 4; ++mi) {
      af[0][mi] = *(const short8*)&A[rbase + mi * 1024 + rs0];
      af[1][mi] = *(const short8*)&A[rbase + mi * 1024 + rs1];
    }
#pragma unroll
    for (int c01 = 0; c01 < 2; ++c01)
#pragma unroll
      for (int mi = 0; mi < 4; ++mi)
#pragma unroll
        for (int ni = 0; ni < 4; ++ni)
          acc[mi][ni] = __builtin_amdgcn_mfma_f32_16x16x32_bf16(
              af[c01][mi], bf[c01][ni], acc[mi][ni], 0, 0, 0);
  };

  issueA(0); loadB(bf0); advance(0);
  __syncthreads();
  for (int it = 0; it < 9; ++it) {
    int s = it * 2;
    issueA(1); loadB(bf1); advance(s + 1);
    compute(0, bf0);
    __syncthreads();
    if (it < 8) { issueA(0); loadB(bf0); advance(s + 2); }
    compute(1, bf1);
    __syncthreads();
  }

  if (MODE == 0) {
    u16* PP = Pp + ((size_t)(cq * 4 + u) * 4096 + pt * 128 + wm * 64 + (l >> 4) * 4) * 128
              + wn * 64 + (l & 15);
#pragma unroll
    for (int mi = 0; mi < 4; ++mi)
#pragma unroll
      for (int ni = 0; ni < 4; ++ni)
#pragma unroll
        for (int jj = 0; jj < 4; ++jj) {
          __hip_bfloat16 hv = __float2bfloat16(acc[mi][ni][jj]);
          PP[(mi * 16 + jj) * 128 + ni * 16] = *(u16*)&hv;
        }
  } else {
    float* ca = convacc + (size_t)u * 4096 * 128;
#pragma unroll
    for (int mi = 0; mi < 4; ++mi)
#pragma unroll
      for (int ni = 0; ni < 4; ++ni)
#pragma unroll
        for (int jj = 0; jj < 4; ++jj) {
          int pos = pt * 128 + wm * 64 + mi * 16 + (l >> 4) * 4 + jj;
          int oc = wn * 64 + ni * 16 + (l & 15);
          atomicAdd(&ca[pos * 128 + oc], acc[mi][ni][jj]);
        }
  }
}

// ---------------- bias + relu + GAP (partial path, vectorized) ----------------
// grid 256 = [u4][g64]; block covers 64 pos; thread: oc octet (t&15)*8, pos-lane t>>4 (4 pos)
__global__ void reduce_gap_p(const u16* __restrict__ P,
                             const float* __restrict__ b2, const float* __restrict__ b4,
                             float* __restrict__ gapacc) {
  int u = blockIdx.x >> 6, g = blockIdx.x & 63;
  int conv = u >> 1;
  const float* bias = conv ? b4 : b2;
  int t = threadIdx.x;
  int oct = (t & 15) * 8, pl = t >> 4;
  float bi[8];
  *(float4*)&bi[0] = *(const float4*)&bias[oct];
  *(float4*)&bi[4] = *(const float4*)&bias[oct + 4];
  float s[8];
#pragma unroll
  for (int e = 0; e < 8; ++e) s[e] = 0.f;
  for (int i = 0; i < 4; ++i) {
    int pos = g * 64 + pl * 4 + i;
    size_t base = ((size_t)u * 4096 + pos) * 128 + oct;
    float v[8];
#pragma unroll
    for (int e = 0; e < 8; ++e) v[e] = bi[e];
#pragma unroll
    for (int cq = 0; cq < 4; ++cq) {
      uint4 q = *(const uint4*)&P[base + (size_t)cq * 2097152];
      unsigned w[4] = {q.x, q.y, q.z, q.w};
#pragma unroll
      for (int k = 0; k < 4; ++k) {
        v[k * 2]     += __builtin_bit_cast(float, (w[k] & 0xffffu) << 16);
        v[k * 2 + 1] += __builtin_bit_cast(float, w[k] & 0xffff0000u);
      }
    }
#pragma unroll
    for (int e = 0; e < 8; ++e) s[e] += v[e] > 0.f ? v[e] : 0.f;
  }
  __shared__ float red[16][128];
#pragma unroll
  for (int e = 0; e < 8; ++e) red[pl][oct + e] = s[e];
  __syncthreads();
  if (t < 128) {
    float acc = 0.f;
#pragma unroll
    for (int r = 0; r < 16; ++r) acc += red[r][t];
    atomicAdd(&gapacc[u * 128 + t], acc);
  }
}

// ---------------- bias + relu + GAP (atomic fallback path) ----------------
__global__ void reduce_gap_a(const float* __restrict__ convacc,
                             const float* __restrict__ b2, const float* __restrict__ b4,
                             float* __restrict__ gapacc) {
  int unit = blockIdx.x >> 5, chunk = blockIdx.x & 31;
  int conv = unit >> 1;
  const float* bias = conv ? b4 : b2;
  int t = threadIdx.x, oc = t & 127, half = t >> 7;
  const float* ca = convacc + (size_t)unit * 4096 * 128;
  float bi = bias[oc];
  float s = 0.f;
  for (int i = 0; i < 64; ++i) {
    int pos = chunk * 128 + half * 64 + i;
    float v = ca[pos * 128 + oc] + bi;
    s += v > 0.f ? v : 0.f;
  }
  __shared__ float red[2][128];
  red[half][oc] = s;
  __syncthreads();
  if (t < 128) atomicAdd(&gapacc[unit * 128 + t], red[0][t] + red[1][t]);
}

// ---------------- dense chain ----------------
__global__ void dense1(const float* __restrict__ gapacc, const float* __restrict__ Wd,
                       float* __restrict__ gv) {
  int o = blockIdx.x, t = threadIdx.x;
  float w = Wd[o * 128 + t];
  float p0 = w * gapacc[2 * 128 + t];
  float p1 = w * gapacc[0 * 128 + t];
  float p2 = w * gapacc[3 * 128 + t];
  float p3 = w * gapacc[1 * 128 + t];
#pragma unroll
  for (int m = 1; m < 64; m <<= 1) {
    p0 += __shfl_xor(p0, m); p1 += __shfl_xor(p1, m);
    p2 += __shfl_xor(p2, m); p3 += __shfl_xor(p3, m);
  }
  __shared__ float red[2][4];
  if ((t & 63) == 0) {
    red[t >> 6][0] = p0; red[t >> 6][1] = p1;
    red[t >> 6][2] = p2; red[t >> 6][3] = p3;
  }
  __syncthreads();
  if (t < 4) {
    const float inv = 1.f / 4096.f;
    gv[t * 512 + o] = (red[0][t] + red[1][t]) * inv;
  }
}

__global__ void dense2(const float* __restrict__ gv, const float* __restrict__ Wcc,
                       const float* __restrict__ bcc, float* __restrict__ zv) {
  int o = blockIdx.x, t = threadIdx.x;
  float w0 = Wcc[o * 512 + t], w1 = Wcc[o * 512 + 256 + t];
  float p[4];
#pragma unroll
  for (int c = 0; c < 4; ++c)
    p[c] = w0 * gv[c * 512 + t] + w1 * gv[c * 512 + 256 + t];
#pragma unroll
  for (int m = 1; m < 64; m <<= 1)
#pragma unroll
    for (int c = 0; c < 4; ++c) p[c] += __shfl_xor(p[c], m);
  __shared__ float red[4][4];
  if ((t & 63) == 0)
#pragma unroll
    for (int c = 0; c < 4; ++c) red[t >> 6][c] = p[c];
  __syncthreads();
  if (t < 4) {
    float s = bcc[o];
#pragma unroll
    for (int wv = 0; wv < 4; ++wv) s += red[wv][t];
    zv[t * 256 + o] = s;
  }
}

__global__ void dense3(const float* __restrict__ zv, const float* __restrict__ Wd2,
                       float* __restrict__ cvec) {
  int o = blockIdx.x, t = threadIdx.x;
  float w = Wd2[o * 256 + t];
  float p0 = w * (zv[0 * 256 + t] + zv[1 * 256 + t]);
  float p1 = w * (zv[2 * 256 + t] + zv[3 * 256 + t]);
#pragma unroll
  for (int m = 1; m < 64; m <<= 1) {
    p0 += __shfl_xor(p0, m);
    p1 += __shfl_xor(p1, m);
  }
  __shared__ float red[4][2];
  if ((t & 63) == 0) { red[t >> 6][0] = p0; red[t >> 6][1] = p1; }
  __syncthreads();
  if (t < 2) {
    float s = red[0][t] + red[1][t] + red[2][t] + red[3][t];
    cvec[t * 512 + o] = s;
  }
}

// ---------------- out = x + cvec[b][ch] ----------------
__global__ void final_add(const float* __restrict__ x, const float* __restrict__ cvec,
                          float* __restrict__ out) {
  int i = blockIdx.x * blockDim.x + threadIdx.x;
  int st = gridDim.x * blockDim.x;
  const float4* x4 = (const float4*)x;
  float4* o4 = (float4*)out;
  for (; i < 1048576; i += st) {
    int flat = i << 2;
    int b = flat >> 21;
    int ch = (flat >> 12) & 511;
    float c = cvec[b * 512 + ch];
    float4 v = x4[i];
    v.x += c; v.y += c; v.z += c; v.w += c;
    o4[i] = v;
  }
}

extern "C" void kernel_launch(void* const* d_in, const int* in_sizes, int n_in,
                              void* d_out, int out_size, void* d_ws, size_t ws_size,
                              hipStream_t stream) {
  const float* x   = (const float*)d_in[0];
  const float* W2  = (const float*)d_in[3];
  const float* b2  = (const float*)d_in[4];
  const float* W4  = (const float*)d_in[7];
  const float* b4  = (const float*)d_in[8];
  const float* Wd  = (const float*)d_in[9];
  const float* Wcc = (const float*)d_in[10];
  const float* bcc = (const float*)d_in[11];
  const float* Wd2 = (const float*)d_in[12];
  float* out = (float*)d_out;

  char* ws = (char*)d_ws;
  u16* xT  = (u16*)(ws + XT_OFF);
  u16* Wr2 = (u16*)(ws + WR2_OFF);

  const bool partial = ws_size >= WS_NEED_P;
  size_t ga_off = partial ? GA_OFF_P : GA_OFF_A;
  float* gapacc = (float*)(ws + ga_off);
  float* gv     = (float*)(ws + ga_off + GV_REL);
  float* zv     = (float*)(ws + ga_off + ZV_REL);
  float* cvec   = (float*)(ws + ga_off + CV_REL);

  prep_misc<<<545, 256, 0, stream>>>(xT, W2, W4, Wr2, gapacc);
  prep_x<<<1024, 256, 0, stream>>>(x, xT);

  if (partial) {
    u16* Pp = (u16*)(ws + P_OFF);
    conv_mfma<0><<<512, 256, 0, stream>>>(xT, Wr2, Pp, nullptr);
    reduce_gap_p<<<256, 256, 0, stream>>>(Pp, b2, b4, gapacc);
  } else {
    float* convacc = (float*)(ws + CA_OFF);
    zero_u4<<<512, 256, 0, stream>>>((uint4*)convacc, CA_BYTES / 16);
    conv_mfma<1><<<512, 256, 0, stream>>>(xT, Wr2, nullptr, convacc);
    reduce_gap_a<<<128, 256, 0, stream>>>(convacc, b2, b4, gapacc);
  }

  dense1<<<512, 128, 0, stream>>>(gapacc, Wd, gv);
  dense2<<<256, 256, 0, stream>>>(gv, Wcc, bcc, zv);
  dense3<<<512, 256, 0, stream>>>(zv, Wd2, cvec);
  final_add<<<2048, 256, 0, stream>>>(x, cvec, out);
}

// Round 6
// 56.417 us; speedup vs baseline: 2.5381x; 1.0399x over previous
//
#include <hip/hip_runtime.h>
#include <hip/hip_bf16.h>

typedef short short8 __attribute__((ext_vector_type(8)));
typedef float f32x4 __attribute__((ext_vector_type(4)));
typedef unsigned short u16;

// ---------------- workspace layout (bytes) ----------------
#define XT_OFF   0
#define XT_BYTES (2*78*78*512*2)                  // 12,460,032
#define WR2_OFF  (XT_OFF + XT_BYTES)
#define WR2_BYTES (2*9*16*8*64*16)                // 2,359,296
#define AFTER_W  (WR2_OFF + WR2_BYTES)            // 14,819,328
// --- partial-store path ---
#define P_OFF    AFTER_W
#define P_BYTES  (4*4*4096*128*2)                 // 16,777,216 (bf16)
#define GA_OFF_P (P_OFF + P_BYTES)
// --- atomic fallback path ---
#define CA_OFF   AFTER_W
#define CA_BYTES (4*4096*128*4)
#define GA_OFF_A (CA_OFF + CA_BYTES)
#define GA_BYTES 2048
#define GV_REL   GA_BYTES
#define ZV_REL   (GV_REL + 4*512*4)
#define CV_REL   (ZV_REL + 4*256*4)
#define TAIL_END (CV_REL + 2*512*4)
#define WS_NEED_P ((size_t)GA_OFF_P + TAIL_END)
#define WS_NEED_A ((size_t)GA_OFF_A + TAIL_END)

static __device__ __forceinline__ void async_cp16(u16* lds, const u16* g) {
  __builtin_amdgcn_global_load_lds(
      (const __attribute__((address_space(1))) void*)g,
      (__attribute__((address_space(3))) void*)lds, 16, 0, 0);
}

// ---------------- zero fill (fallback path only) ----------------
__global__ void zero_u4(uint4* __restrict__ p, int n) {
  int i = blockIdx.x * blockDim.x + threadIdx.x;
  int st = gridDim.x * blockDim.x;
  uint4 z = {0u, 0u, 0u, 0u};
  for (; i < n; i += st) p[i] = z;
}

// ---------------- prep_all: prep_x (0..1023) | halo zero | W pack | gapacc zero ----------------
__global__ void prep_all(const float* __restrict__ x, u16* __restrict__ xT,
                         const float* __restrict__ W2, const float* __restrict__ W4,
                         u16* __restrict__ Wr2, float* __restrict__ gapacc) {
  int bid = blockIdx.x;
  int t = threadIdx.x;
  if (bid < 1024) {
    // x -> xTpad (fp32 NCHW -> bf16 [b][h+7][w+7][c])
    __shared__ float tile[64][65];
    int bh = bid >> 3, cc = bid & 7;
    int b = bh >> 6, h = bh & 63;
    int w = t & 63, cq4 = t >> 6;
    int pi = t >> 2, q = t & 3;
#pragma unroll
    for (int i = 0; i < 16; ++i) {
      int ci = cq4 + i * 4;
      tile[ci][w] = x[((b * 512 + cc * 64 + ci) * 4096) + h * 64 + w];
    }
    __syncthreads();
    union { u16 u[16]; uint4 v[2]; } pk;
#pragma unroll
    for (int k = 0; k < 16; ++k) {
      __hip_bfloat16 hb = __float2bfloat16(tile[q * 16 + k][pi]);
      pk.u[k] = *(u16*)&hb;
    }
    u16* dst = xT + ((size_t)(b * 78 + h + 7) * 78 + (pi + 7)) * 512 + cc * 64 + q * 16;
    *(uint4*)dst = pk.v[0];
    *(uint4*)(dst + 8) = pk.v[1];
  } else if (bid < 1312) {
    // zero the halo of xTpad
    int hb = bid - 1024;
    size_t off; int cnt;
    if (hb < 256) {  // w-strips: h in [7,71), w in [0,7) or [71,78)
      int b = hb >> 7, rem = hb & 127, h = rem >> 1, side = rem & 1;
      off = ((size_t)(b * 78 + 7 + h) * 78 + (side ? 71 : 0)) * 512;
      cnt = 7 * 512;
    } else {          // h-spans: rows [0,7) and [71,78)
      int k = hb - 256;
      int b = k >> 4, topbot = (k >> 3) & 1, ch = k & 7;
      off = ((size_t)b * 78 + (topbot ? 71 : 0)) * 78 * 512 + (size_t)ch * 34944;
      cnt = 34944;
    }
    uint4* p = (uint4*)(xT + off);
    int n = cnt >> 3;
    uint4 z = {0u, 0u, 0u, 0u};
    for (int i = t; i < n; i += blockDim.x) p[i] = z;
  } else if (bid < 1568) {
    // coalesced W pack: one block per (conv, oc)
    int idx = bid - 1312;
    int conv = idx >> 7, o = idx & 127;
    const float* W = conv ? W4 : W2;
    __shared__ float sw[4608];
    const float* src = W + (size_t)o * 4608;
    for (int k = 0; k < 18; ++k) sw[t + k * 256] = src[t + k * 256];
    __syncthreads();
    if (t < 144) {
      int tap = t >> 4, kc = t & 15;
      int wn = o >> 6, ni = (o >> 4) & 3;
      size_t base = (size_t)conv * 589824 + (size_t)(tap * 16 + kc) * 4096
                    + (wn * 4 + ni) * 512;
#pragma unroll
      for (int cg = 0; cg < 4; ++cg) {
        union { u16 h[8]; uint4 v; } pk;
#pragma unroll
        for (int e = 0; e < 8; ++e) {
          __hip_bfloat16 hb = __float2bfloat16(sw[(kc * 32 + cg * 8 + e) * 9 + tap]);
          pk.h[e] = *(u16*)&hb;
        }
        int lane = cg * 16 + (o & 15);
        *(uint4*)(Wr2 + base + lane * 8) = pk.v;
      }
    }
  } else {
    // 256 threads zero all 512 gapacc floats (round-4 lesson: cover the whole buffer)
    gapacc[t] = 0.f;
    gapacc[t + 256] = 0.f;
  }
}

// ---------------- dilated conv via MFMA, BK=64, XCD-sibling-mapped, counted-vmcnt ----------------
// decode: xcd=bid&7, j=bid>>3, cq=j&3, g=j>>2, u=g>>2, pt=(g&3)*8+xcd
// tile 128pos x 128oc; per block K = 9 taps x 128c (c-quarter); 18 steps of BK=64.
// LDS: 2 bufs x 128 rows x 128B; 16B-slot swizzle phys = logical ^ (row&7).
// Barrier discipline (T4): issue order pinned [4x cp16][8x loadB] per half-step via
// sched_barrier(0); at each barrier s_waitcnt vmcnt(8) drains exactly the cp16s,
// leaving the 8 newer B-register loads in flight (compiler tracks their reg deps).
template<int MODE>
__global__ __launch_bounds__(256, 2) void conv_mfma(
    const u16* __restrict__ xT, const u16* __restrict__ Wr2,
    u16* __restrict__ Pp, float* __restrict__ convacc) {
  __shared__ __align__(16) u16 Ab[2][8192];     // 2 x 16KB
  int bid = blockIdx.x;
  int xcd = bid & 7, j = bid >> 3, g = j >> 2, cq = j & 3;
  int u = g >> 2, pt = (g & 3) * 8 + xcd;
  int b = u & 1, conv = u >> 1;
  int d = conv ? 7 : 3;
  int h0 = pt * 2;
  const u16* xb = xT + (size_t)b * (78 * 78 * 512);
  int t = threadIdx.x, l = t & 63, wv = t >> 6;
  int wm = wv >> 1, wn = wv & 1;

  int slog = (l & 7) ^ (l >> 3);
  int wq = wv * 8 + (l >> 3);                    // w within half
  const u16* gA[4];
#pragma unroll
  for (int m = 0; m < 4; ++m) {
    int hh = m >> 1, mh = m & 1;
    gA[m] = xb + ((size_t)(h0 + hh - d + 7) * 78 + (mh * 32 + wq - d + 7)) * 512
            + cq * 128 + slog * 8;
  }
  const char* bB = (const char*)Wr2 + (size_t)conv * 1179648
                   + cq * 32768 + wn * 4096 + l * 16;

  int rbase = (wm * 64 + (l & 15)) * 64;
  int rs0 = (((l >> 4)) ^ (l & 7)) * 8;
  int rs1 = ((4 + (l >> 4)) ^ (l & 7)) * 8;

  f32x4 acc[4][4];
#pragma unroll
  for (int i = 0; i < 4; ++i)
#pragma unroll
    for (int jj = 0; jj < 4; ++jj) acc[i][jj] = (f32x4){0.f, 0.f, 0.f, 0.f};

  short8 bf0[2][4], bf1[2][4];

  auto issueA = [&](int buf) {
#pragma unroll
    for (int m = 0; m < 4; ++m)
      async_cp16(&Ab[buf][m * 2048 + wv * 512], gA[m]);
    __builtin_amdgcn_sched_barrier(0);   // pin: cp16s issue before the B loads
  };
  auto loadB = [&](short8 bf[2][4]) {
#pragma unroll
    for (int c01 = 0; c01 < 2; ++c01)
#pragma unroll
      for (int ni = 0; ni < 4; ++ni)
        bf[c01][ni] = *(const short8*)(bB + c01 * 8192 + ni * 1024);
  };
  auto cbar = [&]() {
    __builtin_amdgcn_sched_barrier(0);
    asm volatile("s_waitcnt vmcnt(8)" ::: "memory");   // cp16s (oldest 4 of 12) done
    __builtin_amdgcn_s_barrier();
    __builtin_amdgcn_sched_barrier(0);
  };
  auto advance = [&](int s) {     // pointers: step s -> s+1
    int dA, dB;
    if (!(s & 1)) { dA = 64; dB = 16384; }       // u16 / bytes
    else {
      dB = 114688;
      int tap = (s + 1) >> 1;
      dA = (tap % 3) ? (512 * d - 64) : (38912 * d - 64);   // u16
    }
#pragma unroll
    for (int m = 0; m < 4; ++m) gA[m] += dA;
    bB += dB;
  };
  auto compute = [&](int buf, short8 bf[2][4]) {
    const u16* A = Ab[buf];
    short8 af[2][4];
#pragma unroll
    for (int mi = 0; mi < 4; ++mi) {
      af[0][mi] = *(const short8*)&A[rbase + mi * 1024 + rs0];
      af[1][mi] = *(const short8*)&A[rbase + mi * 1024 + rs1];
    }
#pragma unroll
    for (int c01 = 0; c01 < 2; ++c01)
#pragma unroll
      for (int mi = 0; mi < 4; ++mi)
#pragma unroll
        for (int ni = 0; ni < 4; ++ni)
          acc[mi][ni] = __builtin_amdgcn_mfma_f32_16x16x32_bf16(
              af[c01][mi], bf[c01][ni], acc[mi][ni], 0, 0, 0);
  };

  issueA(0); loadB(bf0); advance(0);
  cbar();
  for (int it = 0; it < 9; ++it) {
    int s = it * 2;
    issueA(1); loadB(bf1); advance(s + 1);
    compute(0, bf0);
    cbar();
    if (it < 8) { issueA(0); loadB(bf0); advance(s + 2); }
    compute(1, bf1);
    cbar();
  }

  if (MODE == 0) {
    u16* PP = Pp + ((size_t)(cq * 4 + u) * 4096 + pt * 128 + wm * 64 + (l >> 4) * 4) * 128
              + wn * 64 + (l & 15);
#pragma unroll
    for (int mi = 0; mi < 4; ++mi)
#pragma unroll
      for (int ni = 0; ni < 4; ++ni)
#pragma unroll
        for (int jj = 0; jj < 4; ++jj) {
          __hip_bfloat16 hv = __float2bfloat16(acc[mi][ni][jj]);
          PP[(mi * 16 + jj) * 128 + ni * 16] = *(u16*)&hv;
        }
  } else {
    float* ca = convacc + (size_t)u * 4096 * 128;
#pragma unroll
    for (int mi = 0; mi < 4; ++mi)
#pragma unroll
      for (int ni = 0; ni < 4; ++ni)
#pragma unroll
        for (int jj = 0; jj < 4; ++jj) {
          int pos = pt * 128 + wm * 64 + mi * 16 + (l >> 4) * 4 + jj;
          int oc = wn * 64 + ni * 16 + (l & 15);
          atomicAdd(&ca[pos * 128 + oc], acc[mi][ni][jj]);
        }
  }
}

// ---------------- bias + relu + GAP (partial path, vectorized) ----------------
__global__ void reduce_gap_p(const u16* __restrict__ P,
                             const float* __restrict__ b2, const float* __restrict__ b4,
                             float* __restrict__ gapacc) {
  int u = blockIdx.x >> 6, g = blockIdx.x & 63;
  int conv = u >> 1;
  const float* bias = conv ? b4 : b2;
  int t = threadIdx.x;
  int oct = (t & 15) * 8, pl = t >> 4;
  float bi[8];
  *(float4*)&bi[0] = *(const float4*)&bias[oct];
  *(float4*)&bi[4] = *(const float4*)&bias[oct + 4];
  float s[8];
#pragma unroll
  for (int e = 0; e < 8; ++e) s[e] = 0.f;
  for (int i = 0; i < 4; ++i) {
    int pos = g * 64 + pl * 4 + i;
    size_t base = ((size_t)u * 4096 + pos) * 128 + oct;
    float v[8];
#pragma unroll
    for (int e = 0; e < 8; ++e) v[e] = bi[e];
#pragma unroll
    for (int cq = 0; cq < 4; ++cq) {
      uint4 q = *(const uint4*)&P[base + (size_t)cq * 2097152];
      unsigned w[4] = {q.x, q.y, q.z, q.w};
#pragma unroll
      for (int k = 0; k < 4; ++k) {
        v[k * 2]     += __builtin_bit_cast(float, (w[k] & 0xffffu) << 16);
        v[k * 2 + 1] += __builtin_bit_cast(float, w[k] & 0xffff0000u);
      }
    }
#pragma unroll
    for (int e = 0; e < 8; ++e) s[e] += v[e] > 0.f ? v[e] : 0.f;
  }
  __shared__ float red[16][128];
#pragma unroll
  for (int e = 0; e < 8; ++e) red[pl][oct + e] = s[e];
  __syncthreads();
  if (t < 128) {
    float acc = 0.f;
#pragma unroll
    for (int r = 0; r < 16; ++r) acc += red[r][t];
    atomicAdd(&gapacc[u * 128 + t], acc);
  }
}

// ---------------- bias + relu + GAP (atomic fallback path) ----------------
__global__ void reduce_gap_a(const float* __restrict__ convacc,
                             const float* __restrict__ b2, const float* __restrict__ b4,
                             float* __restrict__ gapacc) {
  int unit = blockIdx.x >> 5, chunk = blockIdx.x & 31;
  int conv = unit >> 1;
  const float* bias = conv ? b4 : b2;
  int t = threadIdx.x, oc = t & 127, half = t >> 7;
  const float* ca = convacc + (size_t)unit * 4096 * 128;
  float bi = bias[oc];
  float s = 0.f;
  for (int i = 0; i < 64; ++i) {
    int pos = chunk * 128 + half * 64 + i;
    float v = ca[pos * 128 + oc] + bi;
    s += v > 0.f ? v : 0.f;
  }
  __shared__ float red[2][128];
  red[half][oc] = s;
  __syncthreads();
  if (t < 128) atomicAdd(&gapacc[unit * 128 + t], red[0][t] + red[1][t]);
}

// ---------------- dense chain ----------------
__global__ void dense1(const float* __restrict__ gapacc, const float* __restrict__ Wd,
                       float* __restrict__ gv) {
  int o = blockIdx.x, t = threadIdx.x;
  float w = Wd[o * 128 + t];
  float p0 = w * gapacc[2 * 128 + t];
  float p1 = w * gapacc[0 * 128 + t];
  float p2 = w * gapacc[3 * 128 + t];
  float p3 = w * gapacc[1 * 128 + t];
#pragma unroll
  for (int m = 1; m < 64; m <<= 1) {
    p0 += __shfl_xor(p0, m); p1 += __shfl_xor(p1, m);
    p2 += __shfl_xor(p2, m); p3 += __shfl_xor(p3, m);
  }
  __shared__ float red[2][4];
  if ((t & 63) == 0) {
    red[t >> 6][0] = p0; red[t >> 6][1] = p1;
    red[t >> 6][2] = p2; red[t >> 6][3] = p3;
  }
  __syncthreads();
  if (t < 4) {
    const float inv = 1.f / 4096.f;
    gv[t * 512 + o] = (red[0][t] + red[1][t]) * inv;
  }
}

__global__ void dense2(const float* __restrict__ gv, const float* __restrict__ Wcc,
                       const float* __restrict__ bcc, float* __restrict__ zv) {
  int o = blockIdx.x, t = threadIdx.x;
  float w0 = Wcc[o * 512 + t], w1 = Wcc[o * 512 + 256 + t];
  float p[4];
#pragma unroll
  for (int c = 0; c < 4; ++c)
    p[c] = w0 * gv[c * 512 + t] + w1 * gv[c * 512 + 256 + t];
#pragma unroll
  for (int m = 1; m < 64; m <<= 1)
#pragma unroll
    for (int c = 0; c < 4; ++c) p[c] += __shfl_xor(p[c], m);
  __shared__ float red[4][4];
  if ((t & 63) == 0)
#pragma unroll
    for (int c = 0; c < 4; ++c) red[t >> 6][c] = p[c];
  __syncthreads();
  if (t < 4) {
    float s = bcc[o];
#pragma unroll
    for (int wv = 0; wv < 4; ++wv) s += red[wv][t];
    zv[t * 256 + o] = s;
  }
}

__global__ void dense3(const float* __restrict__ zv, const float* __restrict__ Wd2,
                       float* __restrict__ cvec) {
  int o = blockIdx.x, t = threadIdx.x;
  float w = Wd2[o * 256 + t];
  float p0 = w * (zv[0 * 256 + t] + zv[1 * 256 + t]);
  float p1 = w * (zv[2 * 256 + t] + zv[3 * 256 + t]);
#pragma unroll
  for (int m = 1; m < 64; m <<= 1) {
    p0 += __shfl_xor(p0, m);
    p1 += __shfl_xor(p1, m);
  }
  __shared__ float red[4][2];
  if ((t & 63) == 0) { red[t >> 6][0] = p0; red[t >> 6][1] = p1; }
  __syncthreads();
  if (t < 2) {
    float s = red[0][t] + red[1][t] + red[2][t] + red[3][t];
    cvec[t * 512 + o] = s;
  }
}

// ---------------- out = x + cvec[b][ch] ----------------
__global__ void final_add(const float* __restrict__ x, const float* __restrict__ cvec,
                          float* __restrict__ out) {
  int i = blockIdx.x * blockDim.x + threadIdx.x;
  int st = gridDim.x * blockDim.x;
  const float4* x4 = (const float4*)x;
  float4* o4 = (float4*)out;
  for (; i < 1048576; i += st) {
    int flat = i << 2;
    int b = flat >> 21;
    int ch = (flat >> 12) & 511;
    float c = cvec[b * 512 + ch];
    float4 v = x4[i];
    v.x += c; v.y += c; v.z += c; v.w += c;
    o4[i] = v;
  }
}

extern "C" void kernel_launch(void* const* d_in, const int* in_sizes, int n_in,
                              void* d_out, int out_size, void* d_ws, size_t ws_size,
                              hipStream_t stream) {
  const float* x   = (const float*)d_in[0];
  const float* W2  = (const float*)d_in[3];
  const float* b2  = (const float*)d_in[4];
  const float* W4  = (const float*)d_in[7];
  const float* b4  = (const float*)d_in[8];
  const float* Wd  = (const float*)d_in[9];
  const float* Wcc = (const float*)d_in[10];
  const float* bcc = (const float*)d_in[11];
  const float* Wd2 = (const float*)d_in[12];
  float* out = (float*)d_out;

  char* ws = (char*)d_ws;
  u16* xT  = (u16*)(ws + XT_OFF);
  u16* Wr2 = (u16*)(ws + WR2_OFF);

  const bool partial = ws_size >= WS_NEED_P;
  size_t ga_off = partial ? GA_OFF_P : GA_OFF_A;
  float* gapacc = (float*)(ws + ga_off);
  float* gv     = (float*)(ws + ga_off + GV_REL);
  float* zv     = (float*)(ws + ga_off + ZV_REL);
  float* cvec   = (float*)(ws + ga_off + CV_REL);

  prep_all<<<1569, 256, 0, stream>>>(x, xT, W2, W4, Wr2, gapacc);

  if (partial) {
    u16* Pp = (u16*)(ws + P_OFF);
    conv_mfma<0><<<512, 256, 0, stream>>>(xT, Wr2, Pp, nullptr);
    reduce_gap_p<<<256, 256, 0, stream>>>(Pp, b2, b4, gapacc);
  } else {
    float* convacc = (float*)(ws + CA_OFF);
    zero_u4<<<512, 256, 0, stream>>>((uint4*)convacc, CA_BYTES / 16);
    conv_mfma<1><<<512, 256, 0, stream>>>(xT, Wr2, nullptr, convacc);
    reduce_gap_a<<<128, 256, 0, stream>>>(convacc, b2, b4, gapacc);
  }

  dense1<<<512, 128, 0, stream>>>(gapacc, Wd, gv);
  dense2<<<256, 256, 0, stream>>>(gv, Wcc, bcc, zv);
  dense3<<<512, 256, 0, stream>>>(zv, Wd2, cvec);
  final_add<<<2048, 256, 0, stream>>>(x, cvec, out);
}